// Round 9
// baseline (673.997 us; speedup 1.0000x reference)
//
#include <hip/hip_runtime.h>

constexpr int L      = 128;
constexpr int TDIM   = 1024;
constexpr int NBATCH = 128;
constexpr int START  = L - 2; // 126
constexpr int STOP   = L - 1; // 127
constexpr int BSUB   = 16;    // batches per wave (one wave per block)
constexpr int NBLK   = NBATCH / BSUB; // 8

typedef short bf16x8 __attribute__((ext_vector_type(8)));
typedef float f32x4  __attribute__((ext_vector_type(4)));
typedef int   i32x4  __attribute__((ext_vector_type(4)));

union B4 { i32x4 i; bf16x8 v; };

__device__ __forceinline__ short f2bf(float f) {
    unsigned x = __float_as_uint(f);
    return (short)((x + 0x7fffu + ((x >> 16) & 1u)) >> 16); // RNE
}
__device__ __forceinline__ unsigned pkbf(float lo, float hi) {
    unsigned r;
    asm("v_cvt_pk_bf16_f32 %0, %1, %2" : "=v"(r) : "v"(lo), "v"(hi));
    return r;
}

// ---------------------------------------------------------------------------
// Precompute: pexp = masked bf16 exp(pred), chain-lane-sequential layout.
// byte addr = ((blk*1024 + row)*4 + c)*1024 + lane*16   (verified exact)
// ---------------------------------------------------------------------------
__global__ __launch_bounds__(256)
void crf_pexp(const float* __restrict__ pred, const int* __restrict__ seq_len,
              unsigned short* __restrict__ pexp)
{
    int gid  = blockIdx.x * 256 + threadIdx.x;  // 2,097,152 total
    int lane = gid & 63;
    int c    = (gid >> 6) & 3;
    int row  = (gid >> 8) & 1023;
    int blk  = gid >> 18;
    int l15 = lane & 15, l4 = lane >> 4;
    int b = blk * 16 + l15;
    bool live = row < seq_len[b];

    const float* src = pred + ((size_t)b * TDIM + row) * L + 32 * c + 4 * l4;
    f32x4 v0 = *(const f32x4*)(src);        // T = 2c
    f32x4 v1 = *(const f32x4*)(src + 16);   // T = 2c+1

    float e0[4], e1[4];
#pragma unroll
    for (int r = 0; r < 4; ++r) {
        int s0 = 32 * c + 4 * l4 + r;
        int s1 = s0 + 16;
        e0[r] = (live && s0 < 126) ? __expf(v0[r]) : 0.0f;
        e1[r] = (live && s1 < 126) ? __expf(v1[r]) : 0.0f;
    }
    i32x4 out;
    out[0] = (int)pkbf(e0[0], e0[1]);
    out[1] = (int)pkbf(e0[2], e0[3]);
    out[2] = (int)pkbf(e1[0], e1[1]);
    out[3] = (int)pkbf(e1[2], e1[3]);
    *(i32x4*)((char*)pexp + (size_t)gid * 16) = out;
}

// ---------------------------------------------------------------------------
// Chain: 8 blocks x 1 wave. BRANCHLESS single-BB inner loop.
// K split into two independent 2-deep MFMA chains (accE: kt 0,1; accO: kt 2,3)
// summed at unpack. Renorm scale applied unconditionally via sfac (1 or 2^-64).
// ---------------------------------------------------------------------------
struct PB { i32x4 c[4]; };   // one step's pexp chunk (4 x dwordx4 per lane)
struct PF { f32x4 q[8]; };   // fallback: raw pred row

// stage KT (pairs T=KT and T=KT+4): accSum -> *P*sfac -> max -> pack B[KT]
#define STAGE2(KT, INE, INO, PBUF)                                           \
  {                                                                          \
    f32x4 sA = INE[KT] + INO[KT];                                            \
    f32x4 sB = INE[(KT) + 4] + INO[(KT) + 4];                                \
    if ((KT) == 3) {                                                         \
      bool hit = (tS == srow1);                                              \
      res  = hit ? sB[3] : res;                                              \
      resC = hit ? C : resC;                                                 \
    }                                                                        \
    unsigned wa0 = (unsigned)PBUF.c[(KT) >> 1][((KT) & 1) * 2 + 0];          \
    unsigned wa1 = (unsigned)PBUF.c[(KT) >> 1][((KT) & 1) * 2 + 1];          \
    unsigned wb0 = (unsigned)PBUF.c[((KT) + 4) >> 1][(((KT) + 4) & 1) * 2 + 0]; \
    unsigned wb1 = (unsigned)PBUF.c[((KT) + 4) >> 1][(((KT) + 4) & 1) * 2 + 1]; \
    float p0 = __uint_as_float(wa0 << 16) * sfac;                            \
    float p1 = __uint_as_float(wa0 & 0xffff0000u) * sfac;                    \
    float p2 = __uint_as_float(wa1 << 16) * sfac;                            \
    float p3 = __uint_as_float(wa1 & 0xffff0000u) * sfac;                    \
    float q0 = __uint_as_float(wb0 << 16) * sfac;                            \
    float q1 = __uint_as_float(wb0 & 0xffff0000u) * sfac;                    \
    float q2 = __uint_as_float(wb1 << 16) * sfac;                            \
    float q3 = __uint_as_float(wb1 & 0xffff0000u) * sfac;                    \
    float ua0 = sA[0] * p0, ua1 = sA[1] * p1;                                \
    float ua2 = sA[2] * p2, ua3 = sA[3] * p3;                                \
    float ub0 = sB[0] * q0, ub1 = sB[1] * q1;                                \
    float ub2 = sB[2] * q2, ub3 = sB[3] * q3;                                \
    mloc = fmaxf(mloc, fmaxf(fmaxf(fmaxf(ua0, ua1), fmaxf(ua2, ua3)),        \
                             fmaxf(fmaxf(ub0, ub1), fmaxf(ub2, ub3))));      \
    B[KT].i[0] = (int)pkbf(ua0, ua1);                                        \
    B[KT].i[1] = (int)pkbf(ua2, ua3);                                        \
    B[KT].i[2] = (int)pkbf(ub0, ub1);                                        \
    B[KT].i[3] = (int)pkbf(ub2, ub3);                                        \
    __builtin_amdgcn_sched_group_barrier(0x002, 24, 0);                      \
  }

// MFMA groups: E-chain kt 0 (seed) / 1 (chain), O-chain kt 2 (seed) / 3 (chain)
#define GRP_SEED(OUT, KT)                                                    \
  {                                                                          \
    OUT[0] = __builtin_amdgcn_mfma_f32_16x16x32_bf16(A[0][KT], B[KT].v, Z4, 0, 0, 0); \
    OUT[4] = __builtin_amdgcn_mfma_f32_16x16x32_bf16(A[4][KT], B[KT].v, Z4, 0, 0, 0); \
    OUT[1] = __builtin_amdgcn_mfma_f32_16x16x32_bf16(A[1][KT], B[KT].v, Z4, 0, 0, 0); \
    OUT[5] = __builtin_amdgcn_mfma_f32_16x16x32_bf16(A[5][KT], B[KT].v, Z4, 0, 0, 0); \
    OUT[2] = __builtin_amdgcn_mfma_f32_16x16x32_bf16(A[2][KT], B[KT].v, Z4, 0, 0, 0); \
    OUT[6] = __builtin_amdgcn_mfma_f32_16x16x32_bf16(A[6][KT], B[KT].v, Z4, 0, 0, 0); \
    OUT[3] = __builtin_amdgcn_mfma_f32_16x16x32_bf16(A[3][KT], B[KT].v, Z4, 0, 0, 0); \
    OUT[7] = __builtin_amdgcn_mfma_f32_16x16x32_bf16(A[7][KT], B[KT].v, Z4, 0, 0, 0); \
    __builtin_amdgcn_sched_group_barrier(0x008, 8, 0);                       \
  }
#define GRP_ACC(OUT, KT)                                                     \
  {                                                                          \
    OUT[0] = __builtin_amdgcn_mfma_f32_16x16x32_bf16(A[0][KT], B[KT].v, OUT[0], 0, 0, 0); \
    OUT[4] = __builtin_amdgcn_mfma_f32_16x16x32_bf16(A[4][KT], B[KT].v, OUT[4], 0, 0, 0); \
    OUT[1] = __builtin_amdgcn_mfma_f32_16x16x32_bf16(A[1][KT], B[KT].v, OUT[1], 0, 0, 0); \
    OUT[5] = __builtin_amdgcn_mfma_f32_16x16x32_bf16(A[5][KT], B[KT].v, OUT[5], 0, 0, 0); \
    OUT[2] = __builtin_amdgcn_mfma_f32_16x16x32_bf16(A[2][KT], B[KT].v, OUT[2], 0, 0, 0); \
    OUT[6] = __builtin_amdgcn_mfma_f32_16x16x32_bf16(A[6][KT], B[KT].v, OUT[6], 0, 0, 0); \
    OUT[3] = __builtin_amdgcn_mfma_f32_16x16x32_bf16(A[3][KT], B[KT].v, OUT[3], 0, 0, 0); \
    OUT[7] = __builtin_amdgcn_mfma_f32_16x16x32_bf16(A[7][KT], B[KT].v, OUT[7], 0, 0, 0); \
    __builtin_amdgcn_sched_group_barrier(0x008, 8, 0);                       \
  }

// One step: consume {INE,INO}=D_t -> B (u_t); produce {OE,OO}=D_{t+1}
#define ITER(T_, INE, INO, OE, OO, PBUF)                                     \
  {                                                                          \
    const int tS = (T_);                                                     \
    float mloc = 0.0f;                                                       \
    STAGE2(0, INE, INO, PBUF)                                                \
    STAGE2(1, INE, INO, PBUF)                                                \
    GRP_SEED(OE, 0)                                                          \
    STAGE2(2, INE, INO, PBUF)                                                \
    GRP_SEED(OO, 2)                                                          \
    STAGE2(3, INE, INO, PBUF)                                                \
    C += cadd;                                                               \
    GRP_ACC(OE, 1)                                                           \
    GRP_ACC(OO, 3)                                                           \
    bool tr = (__ballot(mloc > 0x1p80f) != 0ull);                            \
    sfac = tr ? 0x1p-64f : 1.0f;                                             \
    cadd = tr ? 44.3614195558365f : 0.0f;                                    \
    loadPB(PBUF, min(tS + 1, TDIM - 1));                                     \
  }

template<bool PEXP>
__global__ __launch_bounds__(64, 1)
void crf_chain(const float* __restrict__ pred,
               const float* __restrict__ trans,
               const int* __restrict__ seq_len,
               const unsigned short* __restrict__ pexp,
               float* __restrict__ fwd_out)
{
    const int lane = threadIdx.x;
    const int l15 = lane & 15, l4 = lane >> 4;
    const int blk = blockIdx.x;
    const int b   = blk * BSUB + l15;

    // A-frags: A[T][kt] elem e = exp(trans[s][16T + l15]),
    //          s = 16*kt + 64*(e>>2) + 4*l4 + (e&3)      (verified exact)
    bf16x8 A[8][4];
#pragma unroll
    for (int T = 0; T < 8; ++T)
#pragma unroll
        for (int kt = 0; kt < 4; ++kt) {
            bf16x8 v;
#pragma unroll
            for (int e = 0; e < 8; ++e) {
                int s = 16 * kt + 64 * (e >> 2) + 4 * l4 + (e & 3);
                v[e] = f2bf(__expf(trans[s * L + 16 * T + l15]));
            }
            A[T][kt] = v;
        }

    const int srow1 = seq_len[b] + 1;

    int mx = srow1;
#pragma unroll
    for (int d = 1; d < 16; d <<= 1) mx = max(mx, __shfl_xor(mx, d));
    const int tmaxR = __builtin_amdgcn_readfirstlane((mx + 1) & ~1); // even

    B4 B[4];
#pragma unroll
    for (int kt = 0; kt < 4; ++kt) B[kt].i = (i32x4){0, 0, 0, 0};
    if (l4 == 3) B[3].i[3] = 0x3F80;    // START = 1.0 (elem6 low half)

    const f32x4 Z4 = {0.f, 0.f, 0.f, 0.f};   // persistent zero C-operand

    float C = 0.0f;
    float sfac = 1.0f, cadd = 0.0f;
    float res = 1.0f, resC = 0.0f;

    const char*  pxb = (const char*)pexp + (size_t)blk * 1024 * 4096;
    const float* pfb = pred + (size_t)b * TDIM * L + 4 * l4;

    auto loadPB = [&](PB& p, int row) {
        const i32x4* s = (const i32x4*)(pxb + (size_t)row * 4096) + lane;
        p.c[0] = s[0]; p.c[1] = s[64]; p.c[2] = s[128]; p.c[3] = s[192];
    };
    auto loadPF = [&](PF& p, int row) {
        const f32x4* s = (const f32x4*)(pfb + (size_t)row * L);
#pragma unroll
        for (int T = 0; T < 8; ++T) p.q[T] = s[T * 4];
    };

    if constexpr (PEXP) {
        PB pa, pb_;
        loadPB(pa, 0); loadPB(pb_, 1);

        f32x4 XE[8], XO[8], YE[8], YO[8];
        // Prologue: {XE,XO} = split D_1 from initial B (u_0)
        GRP_SEED(XE, 0)
        GRP_ACC (XE, 1)
        GRP_SEED(XO, 2)
        GRP_ACC (XO, 3)

        for (int t0 = 1; t0 < tmaxR; t0 += 2) {
            ITER(t0,     XE, XO, YE, YO, pa )
            ITER(t0 + 1, YE, YO, XE, XO, pb_)
        }
    } else {
        // Fallback (no workspace): serialized steps on raw pred.
        PF fa, fb;
        loadPF(fa, 0); loadPF(fb, 1);
        f32x4 acc[8];
        bool applyScale = false;
        auto stepF = [&](int t, PF& pf, bool chk) {
#pragma unroll
            for (int T = 0; T < 8; ++T)
                acc[T] = __builtin_amdgcn_mfma_f32_16x16x32_bf16(A[T][0], B[0].v, Z4, 0, 0, 0);
#pragma unroll
            for (int kt = 1; kt < 4; ++kt)
#pragma unroll
                for (int T = 0; T < 8; ++T)
                    acc[T] = __builtin_amdgcn_mfma_f32_16x16x32_bf16(A[T][kt], B[kt].v, acc[T], 0, 0, 0);

            bool hit = (t == srow1);
            res  = hit ? acc[7][3] : res;
            resC = hit ? C : resC;

            const bool live = (t < srow1);
            float u[8][4];
#pragma unroll
            for (int T = 0; T < 8; ++T)
#pragma unroll
                for (int r = 0; r < 4; ++r) {
                    bool dead = !live || (T == 7 && l4 == 3 && r >= 2);
                    u[T][r] = dead ? 0.0f : acc[T][r] * __expf(pf.q[T][r]);
                }
            if (applyScale) {
#pragma unroll
                for (int T = 0; T < 8; ++T)
#pragma unroll
                    for (int r = 0; r < 4; ++r) u[T][r] *= 0x1p-64f;
                C += 44.3614195558365f;
            }
            applyScale = false;
            if (chk) {
                float m[8];
#pragma unroll
                for (int T = 0; T < 8; ++T)
                    m[T] = fmaxf(fmaxf(u[T][0], u[T][1]), fmaxf(u[T][2], u[T][3]));
                float mx4 = fmaxf(fmaxf(fmaxf(m[0], m[1]), fmaxf(m[2], m[3])),
                                  fmaxf(fmaxf(m[4], m[5]), fmaxf(m[6], m[7])));
                applyScale = (__ballot(mx4 > 0x1p80f) != 0ull);
            }
#pragma unroll
            for (int kt = 0; kt < 4; ++kt) {
                B[kt].i[0] = (int)pkbf(u[kt][0], u[kt][1]);
                B[kt].i[1] = (int)pkbf(u[kt][2], u[kt][3]);
                B[kt].i[2] = (int)pkbf(u[kt + 4][0], u[kt + 4][1]);
                B[kt].i[3] = (int)pkbf(u[kt + 4][2], u[kt + 4][3]);
            }
            loadPF(pf, min(t + 1, TDIM - 1));
        };
        for (int t0 = 0; t0 < tmaxR; t0 += 2) {
            stepF(t0 + 1, fa, true);
            stepF(t0 + 2, fb, false);
        }
    }

    if (l4 == 3)
        fwd_out[b] = __logf(res) + resC;
}

// ---------------------------------------------------------------------------
// Gold path score (unchanged, verified exact).
// ---------------------------------------------------------------------------
__global__ __launch_bounds__(256)
void crf_score(const float* __restrict__ pred,
               const float* __restrict__ trans,
               const int* __restrict__ tags,
               const int* __restrict__ seq_len,
               float* __restrict__ score_out)
{
    const int b = blockIdx.x;
    const int tid = threadIdx.x;
    const int sl = seq_len[b];
    const int* tg = tags + b * TDIM;

    float s = 0.0f;
    for (int t = tid; t < sl; t += 256) {
        int tag = tg[t];
        s += pred[((long)b * TDIM + t) * L + tag];
        int prev = (t == 0) ? START : tg[t - 1];
        s += trans[prev * L + tag];
    }
    if (tid == 0) s += trans[tg[sl - 1] * L + STOP];

    __shared__ float red[4];
#pragma unroll
    for (int d = 1; d < 64; d <<= 1) s += __shfl_xor(s, d);
    if ((tid & 63) == 0) red[tid >> 6] = s;
    __syncthreads();
    if (tid == 0) score_out[b] = (red[0] + red[1]) + (red[2] + red[3]);
}

__global__ __launch_bounds__(128)
void crf_combine(const float* __restrict__ fwd,
                 const float* __restrict__ real,
                 float* __restrict__ out)
{
    const int tid = threadIdx.x;
    float s = fwd[tid] - real[tid];
#pragma unroll
    for (int d = 1; d < 64; d <<= 1) s += __shfl_xor(s, d);
    __shared__ float red[2];
    if ((tid & 63) == 0) red[tid >> 6] = s;
    __syncthreads();
    if (tid == 0) out[0] = red[0] + red[1];
}

extern "C" void kernel_launch(void* const* d_in, const int* in_sizes, int n_in,
                              void* d_out, int out_size, void* d_ws, size_t ws_size,
                              hipStream_t stream)
{
    const float* pred    = (const float*)d_in[0];
    const float* trans   = (const float*)d_in[1];
    const int*   tags    = (const int*)d_in[2];
    const int*   seq_len = (const int*)d_in[3];

    float* ws   = (float*)d_ws;
    float* fwd  = ws;        // 128 floats
    float* real = ws + 128;  // 128 floats

    const size_t pexp_bytes = (size_t)NBLK * 1024 * 4096; // 33.5 MB
    if (ws_size >= 1024 + pexp_bytes) {
        unsigned short* pexp = (unsigned short*)((char*)d_ws + 1024);
        crf_pexp<<<8192, 256, 0, stream>>>(pred, seq_len, pexp);
        crf_chain<true><<<NBLK, 64, 0, stream>>>(pred, trans, seq_len, pexp, fwd);
    } else {
        crf_chain<false><<<NBLK, 64, 0, stream>>>(pred, trans, seq_len, nullptr, fwd);
    }
    crf_score  <<<NBATCH, 256, 0, stream>>>(pred, trans, tags, seq_len, real);
    crf_combine<<<1, 128, 0, stream>>>(fwd, real, (float*)d_out);
}